// Round 19
// baseline (65.547 us; speedup 1.0000x reference)
//
#include <hip/hip_runtime.h>

typedef __attribute__((ext_vector_type(8))) short short8;
typedef __attribute__((ext_vector_type(4))) float f32x4;

#define MFMA(a, b, c) __builtin_amdgcn_mfma_f32_16x16x32_bf16(a, b, c, 0, 0, 0)

__device__ __forceinline__ unsigned short f2bf16(float f) {
    __bf16 h = (__bf16)f;
    return __builtin_bit_cast(unsigned short, h);
}

// one-instruction packed f32x2 -> bf16x2 (RNE). Scalar __bf16 casts do NOT fuse (R9).
__device__ __forceinline__ unsigned cvtpk(float lo, float hi) {
    unsigned r;
    asm("v_cvt_pk_bf16_f32 %0, %1, %2" : "=v"(r) : "v"(lo), "v"(hi));
    return r;
}

// ---------------- prep: weights -> MFMA A-fragment order (bf16), BN folded ------------
// Channel-permutation trick: logical k = 8g + e maps to physical och = 16*(e>>2)+4g+(e&3)
// so the producing gemm's C-frags ARE the next gemm's B-frag, in-lane.
__global__ void prep_kernel(const float* __restrict__ w1, const float* __restrict__ b1,
                            const float* __restrict__ gamma, const float* __restrict__ beta,
                            const float* __restrict__ mean, const float* __restrict__ var,
                            const float* __restrict__ w2, const float* __restrict__ w3,
                            unsigned short* __restrict__ w1a, unsigned short* __restrict__ w2a,
                            unsigned short* __restrict__ w3a) {
    int idx = blockIdx.x * 256 + threadIdx.x;
    if (idx < 8192) {
        int mt = idx >> 9, r = idx & 511, lane = r >> 3, e = r & 7;
        int o = mt * 16 + (lane & 15);
        int k = ((lane >> 4) << 3) + e;
        float inv = gamma[o] * rsqrtf(var[o] + 1e-5f);
        float v;
        if (k < 27)       v = w1[o * 27 + k] * inv;
        else if (k == 27) v = b1[o] * inv + beta[o] - mean[o] * inv;
        else              v = 0.0f;
        w1a[idx] = f2bf16(v);
    }
    if (idx < 32768) {
        int tile = idx >> 9, r = idx & 511, lane = r >> 3, e = r & 7;
        int kt = tile >> 3, mt = tile & 7;
        int g = lane >> 4;
        int o = mt * 16 + (lane & 15);
        int kphys = kt * 32 + ((e >> 2) << 4) + (g << 2) + (e & 3);
        w2a[idx] = f2bf16(w2[o * 256 + kphys]);
    }
    if (idx < 2048) {
        int kt = idx >> 9, r = idx & 511, lane = r >> 3, e = r & 7;
        int g = lane >> 4;
        int o = lane & 15;
        int kphys = kt * 32 + ((e >> 2) << 4) + (g << 2) + (e & 3);
        w3a[idx] = f2bf16(w3[o * 128 + kphys]);
    }
}

// ---------------- main: TWO 16x16 blocks per workgroup, 64 px per wave ----------------
// 1024 blocks x 512 threads. Waves 0-3 -> tile A (j=2*jj), waves 4-7 -> tile B (j=2*jj+1).
// Keeps 4 waves/SIMD (R16's TLP) while halving per-CU LDS w2 re-read traffic (R18's
// lever, which alone lost TLP). w2s + patches staged once per block for 2 tiles.
__global__ __launch_bounds__(512, 2)
void fused_block_kernel(const float* __restrict__ x,
                        const unsigned short* __restrict__ w1a,
                        const unsigned short* __restrict__ w2a,
                        const unsigned short* __restrict__ w3a,
                        const float* __restrict__ b2, const float* __restrict__ b3,
                        float* __restrict__ out) {
    __shared__ __align__(16) unsigned short w2s[32768];       // 64 KB staged w2 fragments
    __shared__ __align__(16) unsigned short patch[2][972];    // 2 tiles' input patches
    __shared__ float poolW[8][16];
    __shared__ float poolF[2][16];

    int tid = threadIdx.x;
    int bid = blockIdx.x;
    int b  = bid >> 8;            // 4 images
    int br = (bid >> 3) & 31;     // block row
    int jj = bid & 7;             // tile pair: j = 2*jj + hb
    int r0 = br * 16;
    int lane = tid & 63;
    int w = tid >> 6;             // wave 0..7
    int hb = w >> 2;              // which tile of the pair
    int wl = w & 3;               // wave-in-tile: rows 4*wl..4*wl+3 (64 px)
    int g = lane >> 4;            // lane group 0..3
    int c = lane & 15;            // pixel column within fragment

    // ---- stage w2 fragments -> LDS (coalesced, 16 B/thread/iter) ----
    #pragma unroll
    for (int it = 0; it < 8; it++) {
        int off = it * 4096 + tid * 8;        // bf16 elements
        *(uint4*)&w2s[off] = *(const uint4*)&w2a[off];
    }

    // ---- stage BOTH x patches (3ch x 18x18 each, SAME zero-pad) -> bf16 ----
    for (int i = tid; i < 1944; i += 512) {
        int t = i / 972, ii = i - t * 972;
        int ch = ii / 324, rr = (ii % 324) / 18, cc = ii % 18;
        int gr = r0 + rr - 1;
        int gc = (jj * 2 + t) * 32 + cc - 1;
        float v = 0.0f;
        if ((unsigned)gr < 512u && (unsigned)gc < 512u)
            v = x[((b * 3 + ch) * 512 + gr) * 512 + gc];
        patch[t][ii] = f2bf16(v);
    }
    __syncthreads();

    // ---- im2col offsets for this lane's k-octet (k = g*8+e) ----
    int offk[8];
    #pragma unroll
    for (int e = 0; e < 8; e++) {
        int k = g * 8 + e;
        int ch = (k * 7282) >> 16;
        int rem = k - ch * 9;
        int dy = (rem * 21846) >> 16;
        int dx = rem - dy * 3;
        int o = ch * 324 + dy * 18 + dx;
        offk[e] = (k < 27) ? o : 0;
    }

    // ---- build GEMM1 B-fragments in registers (held all kernel) ----
    short8 bfr[4];
    #pragma unroll
    for (int nj = 0; nj < 4; nj++) {
        int base = (4 * wl + nj) * 18 + c;     // px = nj*16+c -> row 4wl+nj, col c
        unsigned val[8];
        #pragma unroll
        for (int e = 0; e < 8; e++)
            val[e] = patch[hb][base + offk[e]];
        if (g == 3) {                          // k=27 -> bias channel 1.0 ; k>27 -> 0
            val[3] = 0x3F80u;
            val[4] = val[5] = val[6] = val[7] = 0u;
        }
        union { unsigned u[4]; short8 s; } uu;
        #pragma unroll
        for (int q = 0; q < 4; q++)
            uu.u[q] = val[2 * q] | (val[2 * q + 1] << 16);
        bfr[nj] = uu.s;
    }

    const f32x4 zero = {0.f, 0.f, 0.f, 0.f};

    // ---- acc2 init = b2 bias (free: C-in of first MFMA) ----
    f32x4 acc2[8][4];
    #pragma unroll
    for (int m = 0; m < 8; m++) {
        f32x4 bb = *(const f32x4*)&b2[m * 16 + g * 4];
        #pragma unroll
        for (int nj = 0; nj < 4; nj++)
            acc2[m][nj] = bb;
    }

    // ---- fused GEMM1 -> GEMM2 in two half-K phases (4 chunks each) ----
    #pragma unroll
    for (int hh = 0; hh < 2; hh++) {
        // PHASE A (half hh): 4 chunks of GEMM1 -> b2fAll[4][4] (64 VGPR)
        short8 b2fAll[4][4];
        #pragma unroll
        for (int k4 = 0; k4 < 4; k4++) {
            int kt = hh * 4 + k4;
            short8 w1f0 = *(const short8*)&w1a[(kt * 2 + 0) * 512 + lane * 8];
            short8 w1f1 = *(const short8*)&w1a[(kt * 2 + 1) * 512 + lane * 8];
            #pragma unroll
            for (int nj = 0; nj < 4; nj++) {
                f32x4 a0 = MFMA(w1f0, bfr[nj], zero);   // och 16*0+4g+i of chunk kt
                f32x4 a1 = MFMA(w1f1, bfr[nj], zero);   // och 16*1+4g+i of chunk kt
                union { unsigned u[4]; short8 s; } uu;
                uu.u[0] = cvtpk(fmaxf(a0[0], 0.f), fmaxf(a0[1], 0.f));
                uu.u[1] = cvtpk(fmaxf(a0[2], 0.f), fmaxf(a0[3], 0.f));
                uu.u[2] = cvtpk(fmaxf(a1[0], 0.f), fmaxf(a1[1], 0.f));
                uu.u[3] = cvtpk(fmaxf(a1[2], 0.f), fmaxf(a1[3], 0.f));
                b2fAll[k4][nj] = uu.s;                  // logical k = 8g+e (permuted w2a)
            }
        }
        // PHASE B (half hh): GEMM2 as pure ds_read + MFMA stream
        #pragma unroll
        for (int k4 = 0; k4 < 4; k4++) {
            int kt = hh * 4 + k4;
            #pragma unroll
            for (int m = 0; m < 8; m++) {
                short8 w2f = *(const short8*)&w2s[(kt * 8 + m) * 512 + lane * 8];
                #pragma unroll
                for (int nj = 0; nj < 4; nj++)
                    acc2[m][nj] = MFMA(w2f, b2fAll[k4][nj], acc2[m][nj]);
            }
        }
    }

    // ---- GEMM3: logits[16][64 px], K=128 over h in 4 chunks of 32 ----
    f32x4 accP[4] = {zero, zero, zero, zero};
    #pragma unroll
    for (int kt = 0; kt < 4; kt++) {
        short8 w3f = *(const short8*)&w3a[kt * 512 + lane * 8];
        #pragma unroll
        for (int nj = 0; nj < 4; nj++) {
            f32x4 a0 = acc2[2 * kt + 0][nj];
            f32x4 a1 = acc2[2 * kt + 1][nj];
            union { unsigned u[4]; short8 s; } uu;
            uu.u[0] = cvtpk(fmaxf(a0[0], 0.f), fmaxf(a0[1], 0.f));
            uu.u[1] = cvtpk(fmaxf(a0[2], 0.f), fmaxf(a0[3], 0.f));
            uu.u[2] = cvtpk(fmaxf(a1[0], 0.f), fmaxf(a1[1], 0.f));
            uu.u[3] = cvtpk(fmaxf(a1[2], 0.f), fmaxf(a1[3], 0.f));
            accP[nj] = MFMA(w3f, uu.s, accP[nj]);
        }
    }

    // ---- pool: sum logits over the wave's 64 px, combine 4 waves per tile ----
    float v0 = accP[0][0] + accP[1][0] + accP[2][0] + accP[3][0];
    float v1 = accP[0][1] + accP[1][1] + accP[2][1] + accP[3][1];
    float v2 = accP[0][2] + accP[1][2] + accP[2][2] + accP[3][2];
    float v3 = accP[0][3] + accP[1][3] + accP[2][3] + accP[3][3];
    #pragma unroll
    for (int off = 1; off < 16; off <<= 1) {
        v0 += __shfl_xor(v0, off);
        v1 += __shfl_xor(v1, off);
        v2 += __shfl_xor(v2, off);
        v3 += __shfl_xor(v3, off);
    }
    if (c == 0) {
        poolW[w][g * 4 + 0] = v0;
        poolW[w][g * 4 + 1] = v1;
        poolW[w][g * 4 + 2] = v2;
        poolW[w][g * 4 + 3] = v3;
    }
    __syncthreads();
    if (tid < 32) {
        int t = tid >> 4, ch = tid & 15;
        float s = poolW[4 * t + 0][ch] + poolW[4 * t + 1][ch] +
                  poolW[4 * t + 2][ch] + poolW[4 * t + 3][ch];
        poolF[t][ch] = s * (1.0f / 256.0f) + b3[ch];
    }
    __syncthreads();

    // ---- broadcast store: 2 rows, out[b][cc][h=r0+2*jj+t][:] = poolF[t][cc] ----
    {
        int t = tid >> 8;                 // 0/1: which tile's row
        int r = tid & 255;
        int cc = r >> 4;                  // channel 0..15
        int base = r & 15;
        int h = r0 + jj * 2 + t;
        float pv = poolF[t][cc];
        float4 vv = {pv, pv, pv, pv};
        float4* rowp = (float4*)(out + (size_t)(((b * 16 + cc) * 512 + h)) * 512);
        #pragma unroll
        for (int ii = 0; ii < 8; ii++)
            rowp[ii * 16 + base] = vv;
    }
}

extern "C" void kernel_launch(void* const* d_in, const int* in_sizes, int n_in,
                              void* d_out, int out_size, void* d_ws, size_t ws_size,
                              hipStream_t stream) {
    const float* x     = (const float*)d_in[0];
    const float* w1    = (const float*)d_in[1];
    const float* b1    = (const float*)d_in[2];
    const float* gamma = (const float*)d_in[3];
    const float* beta  = (const float*)d_in[4];
    const float* mean  = (const float*)d_in[5];
    const float* var   = (const float*)d_in[6];
    const float* w2    = (const float*)d_in[7];
    const float* b2    = (const float*)d_in[8];
    const float* w3    = (const float*)d_in[9];
    const float* b3    = (const float*)d_in[10];
    float* out = (float*)d_out;

    unsigned short* w1a = (unsigned short*)d_ws;        // 8192 bf16
    unsigned short* w2a = w1a + 8192;                   // 32768 bf16
    unsigned short* w3a = w2a + 32768;                  // 2048 bf16

    prep_kernel<<<128, 256, 0, stream>>>(w1, b1, gamma, beta, mean, var, w2, w3,
                                         w1a, w2a, w3a);
    fused_block_kernel<<<1024, 512, 0, stream>>>(x, w1a, w2a, w3a, b2, b3, out);
}

// Round 20
// 54.379 us; speedup vs baseline: 1.2054x; 1.2054x over previous
//
#include <hip/hip_runtime.h>

typedef __attribute__((ext_vector_type(8))) short short8;
typedef __attribute__((ext_vector_type(4))) float f32x4;

#define MFMA(a, b, c) __builtin_amdgcn_mfma_f32_16x16x32_bf16(a, b, c, 0, 0, 0)

__device__ __forceinline__ unsigned short f2bf16(float f) {
    __bf16 h = (__bf16)f;
    return __builtin_bit_cast(unsigned short, h);
}

// one-instruction packed f32x2 -> bf16x2 (RNE). Scalar __bf16 casts do NOT fuse (R9).
__device__ __forceinline__ unsigned cvtpk(float lo, float hi) {
    unsigned r;
    asm("v_cvt_pk_bf16_f32 %0, %1, %2" : "=v"(r) : "v"(lo), "v"(hi));
    return r;
}

// ---------------- prep: weights -> MFMA A-fragment order (bf16), BN folded ------------
// Channel-permutation trick: logical k = 8g + e maps to physical och = 16*(e>>2)+4g+(e&3)
// so the producing gemm's C-frags ARE the next gemm's B-frag, in-lane.
__global__ void prep_kernel(const float* __restrict__ w1, const float* __restrict__ b1,
                            const float* __restrict__ gamma, const float* __restrict__ beta,
                            const float* __restrict__ mean, const float* __restrict__ var,
                            const float* __restrict__ w2, const float* __restrict__ w3,
                            unsigned short* __restrict__ w1a, unsigned short* __restrict__ w2a,
                            unsigned short* __restrict__ w3a) {
    int idx = blockIdx.x * 256 + threadIdx.x;
    if (idx < 8192) {
        int mt = idx >> 9, r = idx & 511, lane = r >> 3, e = r & 7;
        int o = mt * 16 + (lane & 15);
        int k = ((lane >> 4) << 3) + e;
        float inv = gamma[o] * rsqrtf(var[o] + 1e-5f);
        float v;
        if (k < 27)       v = w1[o * 27 + k] * inv;
        else if (k == 27) v = b1[o] * inv + beta[o] - mean[o] * inv;
        else              v = 0.0f;
        w1a[idx] = f2bf16(v);
    }
    if (idx < 32768) {
        int tile = idx >> 9, r = idx & 511, lane = r >> 3, e = r & 7;
        int kt = tile >> 3, mt = tile & 7;
        int g = lane >> 4;
        int o = mt * 16 + (lane & 15);
        int kphys = kt * 32 + ((e >> 2) << 4) + (g << 2) + (e & 3);
        w2a[idx] = f2bf16(w2[o * 256 + kphys]);
    }
    if (idx < 2048) {
        int kt = idx >> 9, r = idx & 511, lane = r >> 3, e = r & 7;
        int g = lane >> 4;
        int o = lane & 15;
        int kphys = kt * 32 + ((e >> 2) << 4) + (g << 2) + (e & 3);
        w3a[idx] = f2bf16(w3[o * 128 + kphys]);
    }
}

// ---------------- main: one 16x16 block (even block-col only) per workgroup -----------
// 2048 blocks x 512 threads (8 waves x 32 px) = R16, with COMPLEMENTARY-PHASE schedule:
// K is split into two halves; odd waves process halves in reversed order (hh = ph^(w&1)).
// At any instant ~half the resident waves are in phase A (MFMA+cvtpk, no LDS) and half
// in phase B (LDS ds_read + MFMA, no VALU) -> VALU and LDS pipes run concurrently on
// complementary wave sets instead of idling alternately. hh is used ONLY in addresses;
// every register-array index is compile-time (rule #20).
__global__ __launch_bounds__(512, 2)
void fused_block_kernel(const float* __restrict__ x,
                        const unsigned short* __restrict__ w1a,
                        const unsigned short* __restrict__ w2a,
                        const unsigned short* __restrict__ w3a,
                        const float* __restrict__ b2, const float* __restrict__ b3,
                        float* __restrict__ out) {
    __shared__ __align__(16) unsigned short w2s[32768];   // 64 KB staged w2 fragments
    __shared__ __align__(16) unsigned short patch[3 * 18 * 18];
    __shared__ float poolW[8][16];
    __shared__ float poolF[16];

    int tid = threadIdx.x;
    int bid = blockIdx.x;
    int b  = bid >> 9;
    int br = (bid >> 4) & 31;
    int j  = bid & 15;            // block col = 2*j (only even block-cols feed the output)
    int r0 = br * 16;
    int c0 = j * 32;
    int lane = tid & 63;
    int w = tid >> 6;             // wave 0..7, owns spatial rows 2w, 2w+1 (32 px)
    int g = lane >> 4;            // lane group 0..3
    int c = lane & 15;            // pixel column within fragment

    // ---- stage w2 fragments -> LDS (coalesced, 16 B/thread/iter) ----
    #pragma unroll
    for (int it = 0; it < 8; it++) {
        int off = it * 4096 + tid * 8;        // bf16 elements
        *(uint4*)&w2s[off] = *(const uint4*)&w2a[off];
    }

    // ---- stage x patch (3ch x 18x18, SAME zero-pad) -> bf16 ----
    for (int i = tid; i < 972; i += 512) {
        int ch = i / 324, rr = (i % 324) / 18, cc = i % 18;
        int gr = r0 + rr - 1, gc = c0 + cc - 1;
        float v = 0.0f;
        if ((unsigned)gr < 512u && (unsigned)gc < 512u)
            v = x[((b * 3 + ch) * 512 + gr) * 512 + gc];
        patch[i] = f2bf16(v);
    }
    __syncthreads();

    // ---- im2col offsets for this lane's k-octet (k = g*8+e) ----
    int offk[8];
    #pragma unroll
    for (int e = 0; e < 8; e++) {
        int k = g * 8 + e;
        int ch = (k * 7282) >> 16;
        int rem = k - ch * 9;
        int dy = (rem * 21846) >> 16;
        int dx = rem - dy * 3;
        int o = ch * 324 + dy * 18 + dx;
        offk[e] = (k < 27) ? o : 0;
    }

    // ---- build GEMM1 B-fragments in registers (held all kernel) ----
    short8 bfr[2];
    #pragma unroll
    for (int nj = 0; nj < 2; nj++) {
        int base = (2 * w + nj) * 18 + c;      // px = nj*16+c -> row 2w+nj, col c
        unsigned val[8];
        #pragma unroll
        for (int e = 0; e < 8; e++)
            val[e] = patch[base + offk[e]];
        if (g == 3) {                          // k=27 -> bias channel 1.0 ; k>27 -> 0
            val[3] = 0x3F80u;
            val[4] = val[5] = val[6] = val[7] = 0u;
        }
        union { unsigned u[4]; short8 s; } uu;
        #pragma unroll
        for (int q = 0; q < 4; q++)
            uu.u[q] = val[2 * q] | (val[2 * q + 1] << 16);
        bfr[nj] = uu.s;
    }

    const f32x4 zero = {0.f, 0.f, 0.f, 0.f};

    f32x4 acc2[8][2];
    #pragma unroll
    for (int m = 0; m < 8; m++) {
        acc2[m][0] = zero;
        acc2[m][1] = zero;
    }

    // ---- fused GEMM1 -> GEMM2, complementary half-K phases across wave parity ----
    int par = w & 1;
    #pragma unroll
    for (int ph = 0; ph < 2; ph++) {
        int hh = ph ^ par;                     // runtime; address-only use
        // PHASE A (half hh): 4 chunks of GEMM1 -> b2fAll[4][2] (32 VGPR)
        short8 b2fAll[4][2];
        #pragma unroll
        for (int k4 = 0; k4 < 4; k4++) {
            int kt = hh * 4 + k4;
            short8 w1f0 = *(const short8*)&w1a[(kt * 2 + 0) * 512 + lane * 8];
            short8 w1f1 = *(const short8*)&w1a[(kt * 2 + 1) * 512 + lane * 8];
            #pragma unroll
            for (int nj = 0; nj < 2; nj++) {
                f32x4 a0 = MFMA(w1f0, bfr[nj], zero);   // och 16*0+4g+i of chunk kt
                f32x4 a1 = MFMA(w1f1, bfr[nj], zero);   // och 16*1+4g+i of chunk kt
                union { unsigned u[4]; short8 s; } uu;
                uu.u[0] = cvtpk(fmaxf(a0[0], 0.f), fmaxf(a0[1], 0.f));
                uu.u[1] = cvtpk(fmaxf(a0[2], 0.f), fmaxf(a0[3], 0.f));
                uu.u[2] = cvtpk(fmaxf(a1[0], 0.f), fmaxf(a1[1], 0.f));
                uu.u[3] = cvtpk(fmaxf(a1[2], 0.f), fmaxf(a1[3], 0.f));
                b2fAll[k4][nj] = uu.s;                  // logical k = 8g+e (permuted w2a)
            }
        }
        // PHASE B (half hh): GEMM2 as pure ds_read + MFMA stream
        #pragma unroll
        for (int k4 = 0; k4 < 4; k4++) {
            int kt = hh * 4 + k4;
            #pragma unroll
            for (int m = 0; m < 8; m++) {
                short8 w2f = *(const short8*)&w2s[(kt * 8 + m) * 512 + lane * 8];
                acc2[m][0] = MFMA(w2f, b2fAll[k4][0], acc2[m][0]);
                acc2[m][1] = MFMA(w2f, b2fAll[k4][1], acc2[m][1]);
            }
        }
    }

    // ---- GEMM3: logits[16][32 px], K=128 over h in 4 chunks of 32 ----
    f32x4 accP[2] = {zero, zero};
    #pragma unroll
    for (int kt = 0; kt < 4; kt++) {
        short8 w3f = *(const short8*)&w3a[kt * 512 + lane * 8];
        f32x4 bA = *(const f32x4*)&b2[(2 * kt + 0) * 16 + g * 4];
        f32x4 bB = *(const f32x4*)&b2[(2 * kt + 1) * 16 + g * 4];
        #pragma unroll
        for (int nj = 0; nj < 2; nj++) {
            f32x4 a0 = acc2[2 * kt + 0][nj];
            f32x4 a1 = acc2[2 * kt + 1][nj];
            union { unsigned u[4]; short8 s; } uu;
            uu.u[0] = cvtpk(fmaxf(a0[0] + bA[0], 0.f), fmaxf(a0[1] + bA[1], 0.f));
            uu.u[1] = cvtpk(fmaxf(a0[2] + bA[2], 0.f), fmaxf(a0[3] + bA[3], 0.f));
            uu.u[2] = cvtpk(fmaxf(a1[0] + bB[0], 0.f), fmaxf(a1[1] + bB[1], 0.f));
            uu.u[3] = cvtpk(fmaxf(a1[2] + bB[2], 0.f), fmaxf(a1[3] + bB[3], 0.f));
            accP[nj] = MFMA(w3f, uu.s, accP[nj]);
        }
    }

    // ---- pool: sum logits over this wave's 32 px, combine across 8 waves ----
    float v0 = accP[0][0] + accP[1][0];
    float v1 = accP[0][1] + accP[1][1];
    float v2 = accP[0][2] + accP[1][2];
    float v3 = accP[0][3] + accP[1][3];
    #pragma unroll
    for (int off = 1; off < 16; off <<= 1) {
        v0 += __shfl_xor(v0, off);
        v1 += __shfl_xor(v1, off);
        v2 += __shfl_xor(v2, off);
        v3 += __shfl_xor(v3, off);
    }
    if (c == 0) {
        poolW[w][g * 4 + 0] = v0;
        poolW[w][g * 4 + 1] = v1;
        poolW[w][g * 4 + 2] = v2;
        poolW[w][g * 4 + 3] = v3;
    }
    __syncthreads();
    if (tid < 16) {
        float s = 0.f;
        #pragma unroll
        for (int ww = 0; ww < 8; ww++) s += poolW[ww][tid];
        poolF[tid] = s * (1.0f / 256.0f) + b3[tid];
    }
    __syncthreads();

    // ---- broadcast store: out[b][cc][h=br*16+j][:] = poolF[cc] ----
    int h = r0 + j;
    int cc = tid >> 5;
    float pv = poolF[cc];
    float4 vv = {pv, pv, pv, pv};
    float4* rowp = (float4*)(out + (size_t)(((b * 16 + cc) * 512 + h)) * 512);
    int base = tid & 31;
    #pragma unroll
    for (int ii = 0; ii < 4; ii++)
        rowp[ii * 32 + base] = vv;
}

extern "C" void kernel_launch(void* const* d_in, const int* in_sizes, int n_in,
                              void* d_out, int out_size, void* d_ws, size_t ws_size,
                              hipStream_t stream) {
    const float* x     = (const float*)d_in[0];
    const float* w1    = (const float*)d_in[1];
    const float* b1    = (const float*)d_in[2];
    const float* gamma = (const float*)d_in[3];
    const float* beta  = (const float*)d_in[4];
    const float* mean  = (const float*)d_in[5];
    const float* var   = (const float*)d_in[6];
    const float* w2    = (const float*)d_in[7];
    const float* b2    = (const float*)d_in[8];
    const float* w3    = (const float*)d_in[9];
    const float* b3    = (const float*)d_in[10];
    float* out = (float*)d_out;

    unsigned short* w1a = (unsigned short*)d_ws;        // 8192 bf16
    unsigned short* w2a = w1a + 8192;                   // 32768 bf16
    unsigned short* w3a = w2a + 32768;                  // 2048 bf16

    prep_kernel<<<128, 256, 0, stream>>>(w1, b1, gamma, beta, mean, var, w2, w3,
                                         w1a, w2a, w3a);
    fused_block_kernel<<<2048, 512, 0, stream>>>(x, w1a, w2a, w3a, b2, b3, out);
}